// Round 6
// baseline (291.838 us; speedup 1.0000x reference)
//
#include <hip/hip_runtime.h>
#include <stdint.h>

#define HDIM  768
#define VOCAB 30522
#define NNODE 10002      // NEW_ROWS - 2
#define NEDGE 50000
#define NROWS 10004
#define SLOPE 0.2f
#define CAP   32         // per-dst edge slots (deg ~ Poisson(5), max ~18)
#define RCAP  32         // per-node output-row slots (rows/node ~ Poisson(0.8))
#define NROWT 32768      // output rows = 64*512

// ---------- ws layout (bytes) ----------
constexpr size_t OFF_H    = 0;                                   // h bf16 [NNODE*HDIM]
constexpr size_t SZ_HB    = (size_t)NNODE * HDIM * 2;            // 15,363,072
constexpr size_t OFF_FB   = OFF_H + SZ_HB;                       // featbf bf16
constexpr size_t OFF_WT   = OFF_FB + SZ_HB;                      // W^T bf16 [768*768]
constexpr size_t OFF_WAS  = OFF_WT + (size_t)HDIM * HDIM * 2;    // f32[768]
constexpr size_t OFF_WAD  = OFF_WAS + HDIM * 4;
constexpr size_t SZ_N4    = 40032;                               // (NNODE+6)*4 padded
constexpr size_t OFF_SS   = OFF_WAD + HDIM * 4;                  // s_src f32[NNODE]
constexpr size_t OFF_SD   = OFF_SS + SZ_N4;
constexpr size_t OFF_CNT  = OFF_SD + SZ_N4;                      // edge degree counts (zeroed)
constexpr size_t OFF_NCT  = OFF_CNT + SZ_N4;                     // per-node out-row counts (zeroed)
constexpr size_t OFF_SLOT = OFF_NCT + SZ_N4;                     // ushort[NNODE*CAP]
constexpr size_t OFF_NL   = OFF_SLOT + (size_t)NNODE * CAP * 2;  // int[NNODE*RCAP]
// end ~= 34 MB
constexpr int    ZERO_CNT = 10008 + 10008;                       // ints to zero (CNT..NCT contiguous)

// ---------- helpers ----------
__device__ __forceinline__ unsigned short f2bf(float f) {
  unsigned int u = __float_as_uint(f);
  u += 0x7FFFu + ((u >> 16) & 1u);
  return (unsigned short)(u >> 16);
}
__device__ __forceinline__ float bf2f(unsigned short b) {
  return __uint_as_float(((unsigned int)b) << 16);
}

typedef __attribute__((ext_vector_type(8))) short bf16x8;
typedef __attribute__((ext_vector_type(4))) float f32x4;

__device__ __forceinline__ void gl2lds16(const unsigned short* g, unsigned short* l) {
  __builtin_amdgcn_global_load_lds(
      (const __attribute__((address_space(1))) unsigned int*)g,
      (__attribute__((address_space(3))) unsigned int*)l, 16, 0, 0);
}

__device__ __forceinline__ void fma12(float* acc, float ex,
                                      const unsigned short* hr, int lane) {
  const ushort4* p = (const ushort4*)(hr + lane * 12);   // 24B per lane, 8B-aligned
  ushort4 u0 = p[0], u1 = p[1], u2 = p[2];
  acc[0] += ex * bf2f(u0.x); acc[1]  += ex * bf2f(u0.y);
  acc[2] += ex * bf2f(u0.z); acc[3]  += ex * bf2f(u0.w);
  acc[4] += ex * bf2f(u1.x); acc[5]  += ex * bf2f(u1.y);
  acc[6] += ex * bf2f(u1.z); acc[7]  += ex * bf2f(u1.w);
  acc[8] += ex * bf2f(u2.x); acc[9]  += ex * bf2f(u2.y);
  acc[10]+= ex * bf2f(u2.z); acc[11] += ex * bf2f(u2.w);
}

// ---------- K0: wa vectors (blocks 0..191) + zero counters (192..271) ----------
__global__ __launch_bounds__(256) void k_pre(const float* __restrict__ W,
                                             const float* __restrict__ a_s,
                                             const float* __restrict__ a_d,
                                             float* __restrict__ wa_s,
                                             float* __restrict__ wa_d,
                                             int* __restrict__ count) {
  int bid = blockIdx.x, tid = threadIdx.x;
  if (bid >= 192) {                      // zero count + nct (contiguous ints)
    int i = (bid - 192) * 256 + tid;
    if (i < ZERO_CNT) count[i] = 0;
    return;
  }
  int lane = tid & 63, wv = tid >> 6;
  int row = bid * 4 + wv;                // 768 rows
  float ss = 0.f, sd = 0.f;
  for (int n = lane; n < HDIM; n += 64) {
    float w = W[(size_t)row * HDIM + n];
    ss += w * a_s[n];
    sd += w * a_d[n];
  }
#pragma unroll
  for (int off = 32; off; off >>= 1) {
    ss += __shfl_down(ss, off, 64);
    sd += __shfl_down(sd, off, 64);
  }
  if (lane == 0) { wa_s[row] = ss; wa_d[row] = sd; }
}

// ---------- K1: convert+scores [0,2501) | W^T [2501,3077) | scatter [3077,3273) ----------
__global__ __launch_bounds__(256) void k_stage1(const float* __restrict__ feat,
                                                const float* __restrict__ wa_s,
                                                const float* __restrict__ wa_d,
                                                const float* __restrict__ W,
                                                const int* __restrict__ ei,
                                                unsigned short* __restrict__ featbf,
                                                float* __restrict__ s_s,
                                                float* __restrict__ s_d,
                                                unsigned short* __restrict__ wT,
                                                int* __restrict__ count,
                                                unsigned short* __restrict__ slots) {
  int bid = blockIdx.x, tid = threadIdx.x;
  if (bid < 2501) {                      // ---- convert feat->bf16 + fused score dots ----
    int lane = tid & 63, wv = tid >> 6;
    int r = bid * 4 + wv;
    if (r >= NNODE) return;
    const float4* fr = (const float4*)(feat + (size_t)r * HDIM);
    ushort4* ob = (ushort4*)(featbf + (size_t)r * HDIM);
    float ss = 0.f, sd = 0.f;
#pragma unroll
    for (int i = 0; i < 3; ++i) {
      int c = lane + i * 64;
      float4 v = fr[c];
      float4 vs = ((const float4*)wa_s)[c];
      float4 vd = ((const float4*)wa_d)[c];
      ss += v.x * vs.x + v.y * vs.y + v.z * vs.z + v.w * vs.w;
      sd += v.x * vd.x + v.y * vd.y + v.z * vd.z + v.w * vd.w;
      ushort4 o;
      o.x = f2bf(v.x); o.y = f2bf(v.y); o.z = f2bf(v.z); o.w = f2bf(v.w);
      ob[c] = o;
    }
#pragma unroll
    for (int off = 32; off; off >>= 1) {
      ss += __shfl_down(ss, off, 64);
      sd += __shfl_down(sd, off, 64);
    }
    if (lane == 0) { s_s[r] = ss; s_d[r] = sd; }
    return;
  }
  if (bid < 3077) {                      // ---- W -> W^T bf16, 32x32 tiles ----
    __shared__ float tile[32][33];
    int b2 = bid - 2501;
    int tx0 = (b2 % 24) * 32, ty0 = (b2 / 24) * 32;
    int cx = tid & 31, cy = tid >> 5;
#pragma unroll
    for (int r = 0; r < 4; ++r)
      tile[cy + r * 8][cx] = W[(size_t)(ty0 + cy + r * 8) * HDIM + tx0 + cx];
    __syncthreads();
#pragma unroll
    for (int r = 0; r < 4; ++r)
      wT[(size_t)(tx0 + cy + r * 8) * HDIM + ty0 + cx] = f2bf(tile[cx][cy + r * 8]);
    return;
  }
  // ---- slotted edge scatter ----
  int e = (bid - 3077) * 256 + tid;
  if (e < NEDGE) {
    int src = ei[e], dst = ei[NEDGE + e];
    int pos = atomicAdd(count + dst, 1);
    if (pos < CAP) slots[dst * CAP + pos] = (unsigned short)src;
  }
}

// ---------- K2: GEMM (bid%10==0, 942 tiles) || gatherA + node row-list (rest) ----------
// grid 9420: fine interleave keeps MFMA-heavy and BW-heavy blocks co-resident per CU.
__global__ __launch_bounds__(256) void k_stage2(const unsigned short* __restrict__ A,
                                                const unsigned short* __restrict__ BT,
                                                unsigned short* __restrict__ Hout,
                                                const int* __restrict__ x,
                                                const float* __restrict__ orig,
                                                const float* __restrict__ nw,
                                                const float* __restrict__ soft,
                                                int* __restrict__ nct,
                                                int* __restrict__ nlist,
                                                float* __restrict__ out) {
  int bid = blockIdx.x, tid = threadIdx.x;
  int lane = tid & 63, wv = tid >> 6;
  if (bid % 10 != 0) {                   // ---- gatherA: 4 output rows per block ----
    int gather_id = bid - bid / 10 - 1;
    if (gather_id >= 8192) return;
    int row = gather_id * 4 + wv;        // wave = one output row
    int s = row & 511;
    const float* src;
    if (s < 8) {
      src = soft + (size_t)s * HDIM;
    } else {
      int idx = x[row];
      if (idx >= VOCAB && idx < VOCAB + NNODE) {   // node token -> defer to K3
        if (lane == 0) {
          int node = idx - VOCAB;
          int p = atomicAdd(nct + node, 1);
          if (p < RCAP) nlist[node * RCAP + p] = row;
        }
        return;
      }
      src = (idx < VOCAB) ? orig + (size_t)idx * HDIM
                          : nw + (size_t)(NROWS - 1) * HDIM;
    }
    const uint4* s4 = (const uint4*)src;
    uint4* d4 = (uint4*)(out + (size_t)row * HDIM);
    d4[lane]       = s4[lane];
    d4[lane + 64]  = s4[lane + 64];
    d4[lane + 128] = s4[lane + 128];
    return;
  }
  // ---- GEMM tile: 157 M-tiles x 6 N-tiles (64x128), proven round-3 code ----
  int b = bid / 10;
  __shared__ __align__(16) unsigned short As[64 * 32];    // 4 KB
  __shared__ __align__(16) unsigned short Bs[128 * 32];   // 8 KB
  int m0 = (b % 157) * 64, n0 = (b / 157) * 128;
  int q = lane >> 4, lr = lane & 15;

  f32x4 acc[4][2];
#pragma unroll
  for (int i = 0; i < 4; ++i)
#pragma unroll
    for (int j = 0; j < 2; ++j) acc[i][j] = 0.f;

  for (int kt = 0; kt < 24; ++kt) {
    int k0 = kt * 32;
    {
      int row = tid >> 2, kk = (tid & 3) << 3;
      int grow = m0 + row;
      grow = grow <= NNODE - 1 ? grow : NNODE - 1;
      gl2lds16(A + (size_t)grow * HDIM + k0 + kk, As + (size_t)wv * 512);
    }
#pragma unroll
    for (int t = 0; t < 2; ++t) {
      int c = wv * 128 + t * 64 + lane;
      int row = c >> 2, kk = (c & 3) << 3;
      gl2lds16(BT + (size_t)(n0 + row) * HDIM + k0 + kk, Bs + (size_t)wv * 1024 + t * 512);
    }
    __syncthreads();
    bf16x8 a[4], bb[2];
#pragma unroll
    for (int i = 0; i < 4; ++i)
      a[i] = *(const bf16x8*)(As + (i * 16 + lr) * 32 + q * 8);
#pragma unroll
    for (int j = 0; j < 2; ++j)
      bb[j] = *(const bf16x8*)(Bs + (wv * 32 + j * 16 + lr) * 32 + q * 8);
#pragma unroll
    for (int i = 0; i < 4; ++i)
#pragma unroll
      for (int j = 0; j < 2; ++j)
        acc[i][j] = __builtin_amdgcn_mfma_f32_16x16x32_bf16(a[i], bb[j], acc[i][j], 0, 0, 0);
    __syncthreads();
  }
#pragma unroll
  for (int i = 0; i < 4; ++i) {
    int mbase = m0 + i * 16 + q * 4;
#pragma unroll
    for (int j = 0; j < 2; ++j) {
      int n = n0 + wv * 32 + j * 16 + lr;
#pragma unroll
      for (int rg = 0; rg < 4; ++rg) {
        int m = mbase + rg;
        if (m < NNODE) Hout[(size_t)m * HDIM + n] = f2bf(acc[i][j][rg]);
      }
    }
  }
}

// ---------- K3: aggregate per needed node (wave/node) -> write DIRECT to out rows ----------
__global__ __launch_bounds__(256) void k_aggregate(const int* __restrict__ count,
                                                   const unsigned short* __restrict__ slots,
                                                   const float* __restrict__ s_s,
                                                   const float* __restrict__ s_d,
                                                   const unsigned short* __restrict__ h,
                                                   const float* __restrict__ feat,
                                                   const int* __restrict__ nct,
                                                   const int* __restrict__ nlist,
                                                   float* __restrict__ out) {
  int lane = threadIdx.x & 63, wv = threadIdx.x >> 6;
  int n = blockIdx.x * 4 + wv;           // wave = one node; lane owns 12 columns
  if (n >= NNODE) return;
  int rows = nct[n];
  if (rows == 0) return;                 // node never gathered -> no output row
  rows = rows < RCAP ? rows : RCAP;
  int deg = count[n]; deg = deg < CAP ? deg : CAP;
  const unsigned short* sl = slots + n * CAP;
  float sdn = s_d[n];
  float mx = -3.4e38f;
  for (int e = 0; e < deg; ++e) {
    float v = s_s[sl[e]] + sdn;
    v = v > 0.f ? v : SLOPE * v;
    mx = fmaxf(mx, v);
  }
  float den = 0.f;
  float acc[12];
#pragma unroll
  for (int j = 0; j < 12; ++j) acc[j] = 0.f;
  int e = 0;
  for (; e + 1 < deg; e += 2) {          // 2 independent h-row gathers in flight
    int s0 = sl[e], s1 = sl[e + 1];
    float v0 = s_s[s0] + sdn; v0 = v0 > 0.f ? v0 : SLOPE * v0;
    float v1 = s_s[s1] + sdn; v1 = v1 > 0.f ? v1 : SLOPE * v1;
    float ex0 = __expf(v0 - mx), ex1 = __expf(v1 - mx);
    den += ex0 + ex1;
    fma12(acc, ex0, h + (size_t)s0 * HDIM, lane);
    fma12(acc, ex1, h + (size_t)s1 * HDIM, lane);
  }
  if (e < deg) {
    int s0 = sl[e];
    float v0 = s_s[s0] + sdn; v0 = v0 > 0.f ? v0 : SLOPE * v0;
    float ex0 = __expf(v0 - mx);
    den += ex0;
    fma12(acc, ex0, h + (size_t)s0 * HDIM, lane);
  }
  float inv = 1.f / (den + 1e-16f);      // deg==0: acc=0 -> out=feat
  const float4* fr = (const float4*)(feat + (size_t)n * HDIM + lane * 12);
  float4 f0 = fr[0], f1 = fr[1], f2 = fr[2];
  f0.x += acc[0] * inv;  f0.y += acc[1] * inv;
  f0.z += acc[2] * inv;  f0.w += acc[3] * inv;
  f1.x += acc[4] * inv;  f1.y += acc[5] * inv;
  f1.z += acc[6] * inv;  f1.w += acc[7] * inv;
  f2.x += acc[8] * inv;  f2.y += acc[9] * inv;
  f2.z += acc[10] * inv; f2.w += acc[11] * inv;
  for (int ri = 0; ri < rows; ++ri) {
    int r = nlist[n * RCAP + ri];
    float4* d = (float4*)(out + (size_t)r * HDIM + lane * 12);
    d[0] = f0; d[1] = f1; d[2] = f2;
  }
}

// ---------- launch ----------
extern "C" void kernel_launch(void* const* d_in, const int* in_sizes, int n_in,
                              void* d_out, int out_size, void* d_ws, size_t ws_size,
                              hipStream_t stream) {
  const int* x    = (const int*)d_in[0];
  const int* ei   = (const int*)d_in[1];
  const float* og = (const float*)d_in[2];
  const float* nw = (const float*)d_in[3];
  const float* sp = (const float*)d_in[4];
  const float* W  = (const float*)d_in[5];
  const float* as = (const float*)d_in[6];
  const float* ad = (const float*)d_in[7];
  const float* feat = nw + HDIM;                  // new_weight rows 1..10002

  char* ws = (char*)d_ws;
  unsigned short* hbuf   = (unsigned short*)(ws + OFF_H);
  unsigned short* featbf = (unsigned short*)(ws + OFF_FB);
  unsigned short* wT     = (unsigned short*)(ws + OFF_WT);
  float* wa_s            = (float*)(ws + OFF_WAS);
  float* wa_d            = (float*)(ws + OFF_WAD);
  float* s_s             = (float*)(ws + OFF_SS);
  float* s_d             = (float*)(ws + OFF_SD);
  int* count             = (int*)(ws + OFF_CNT);
  int* nct               = (int*)(ws + OFF_NCT);
  unsigned short* slots  = (unsigned short*)(ws + OFF_SLOT);
  int* nlist             = (int*)(ws + OFF_NL);
  float* out             = (float*)d_out;

  // K0: wa vectors + zero counters
  k_pre<<<272, 256, 0, stream>>>(W, as, ad, wa_s, wa_d, count);
  // K1: convert+scores | W^T | slotted scatter
  k_stage1<<<3273, 256, 0, stream>>>(feat, wa_s, wa_d, W, ei,
                                     featbf, s_s, s_d, wT, count, slots);
  // K2: GEMM || gatherA (non-node rows) + node row-list
  k_stage2<<<9420, 256, 0, stream>>>(featbf, wT, hbuf, x, og, nw, sp,
                                     nct, nlist, out);
  // K3: aggregate -> direct output-row writes
  k_aggregate<<<(NNODE + 3) / 4, 256, 0, stream>>>(count, slots, s_s, s_d,
                                                   hbuf, feat, nct, nlist, out);
}

// Round 9
// 261.473 us; speedup vs baseline: 1.1161x; 1.1161x over previous
//
#include <hip/hip_runtime.h>
#include <stdint.h>

#define HDIM  768
#define VOCAB 30522
#define NNODE 10002      // NEW_ROWS - 2
#define NEDGE 50000
#define NROWS 10004
#define SLOPE 0.2f
#define CAP   32         // per-dst edge slots (deg ~ Poisson(5), max ~18)
#define RCAP  32         // per-node output-row slots

// ---------- ws layout (bytes) ----------
constexpr size_t OFF_H    = 0;                                   // h bf16 [NNODE*HDIM]
constexpr size_t SZ_HB    = (size_t)NNODE * HDIM * 2;            // 15,363,072
constexpr size_t OFF_FB   = OFF_H + SZ_HB;                       // featbf bf16
constexpr size_t OFF_WT   = OFF_FB + SZ_HB;                      // W^T bf16 [768*768]
constexpr size_t OFF_WAS  = OFF_WT + (size_t)HDIM * HDIM * 2;    // f32[768]
constexpr size_t OFF_WAD  = OFF_WAS + HDIM * 4;
constexpr size_t SZ_N4    = 40032;                               // (NNODE+6)*4 padded
constexpr size_t OFF_SS   = OFF_WAD + HDIM * 4;                  // s_src f32[NNODE]
constexpr size_t OFF_SD   = OFF_SS + SZ_N4;
constexpr size_t OFF_CNT  = OFF_SD + SZ_N4;                      // edge degree counts (zeroed)
constexpr size_t OFF_NCT  = OFF_CNT + SZ_N4;                     // per-node out-row counts (zeroed)
constexpr size_t OFF_SLOT = OFF_NCT + SZ_N4;                     // ushort[NNODE*CAP]
constexpr size_t OFF_NL   = OFF_SLOT + (size_t)NNODE * CAP * 2;  // int[NNODE*RCAP]
constexpr int    ZERO_CNT = 10008 + 10008;                       // ints to zero (CNT..NCT contiguous)

// ---------- helpers ----------
__device__ __forceinline__ unsigned short f2bf(float f) {
  unsigned int u = __float_as_uint(f);
  u += 0x7FFFu + ((u >> 16) & 1u);
  return (unsigned short)(u >> 16);
}
__device__ __forceinline__ float bf2f(unsigned short b) {
  return __uint_as_float(((unsigned int)b) << 16);
}

typedef __attribute__((ext_vector_type(8))) short bf16x8;
typedef __attribute__((ext_vector_type(4))) float f32x4;

__device__ __forceinline__ void gl2lds16(const unsigned short* g, unsigned short* l) {
  __builtin_amdgcn_global_load_lds(
      (const __attribute__((address_space(1))) unsigned int*)g,
      (__attribute__((address_space(3))) unsigned int*)l, 16, 0, 0);
}

__device__ __forceinline__ void fma12(float* acc, float ex,
                                      const unsigned short* hr, int lane) {
  const ushort4* p = (const ushort4*)(hr + lane * 12);   // 24B per lane, 8B-aligned
  ushort4 u0 = p[0], u1 = p[1], u2 = p[2];
  acc[0] += ex * bf2f(u0.x); acc[1]  += ex * bf2f(u0.y);
  acc[2] += ex * bf2f(u0.z); acc[3]  += ex * bf2f(u0.w);
  acc[4] += ex * bf2f(u1.x); acc[5]  += ex * bf2f(u1.y);
  acc[6] += ex * bf2f(u1.z); acc[7]  += ex * bf2f(u1.w);
  acc[8] += ex * bf2f(u2.x); acc[9]  += ex * bf2f(u2.y);
  acc[10]+= ex * bf2f(u2.z); acc[11] += ex * bf2f(u2.w);
}

// ---------- K0: wa vectors (blocks 0..191) + zero counters (192..271) ----------
__global__ __launch_bounds__(256) void k_pre(const float* __restrict__ W,
                                             const float* __restrict__ a_s,
                                             const float* __restrict__ a_d,
                                             float* __restrict__ wa_s,
                                             float* __restrict__ wa_d,
                                             int* __restrict__ count) {
  int bid = blockIdx.x, tid = threadIdx.x;
  if (bid >= 192) {                      // zero count + nct (contiguous ints)
    int i = (bid - 192) * 256 + tid;
    if (i < ZERO_CNT) count[i] = 0;
    return;
  }
  int lane = tid & 63, wv = tid >> 6;
  int row = bid * 4 + wv;                // 768 rows
  float ss = 0.f, sd = 0.f;
  for (int n = lane; n < HDIM; n += 64) {
    float w = W[(size_t)row * HDIM + n];
    ss += w * a_s[n];
    sd += w * a_d[n];
  }
#pragma unroll
  for (int off = 32; off; off >>= 1) {
    ss += __shfl_down(ss, off, 64);
    sd += __shfl_down(sd, off, 64);
  }
  if (lane == 0) { wa_s[row] = ss; wa_d[row] = sd; }
}

// ---------- K1: convert+scores [0,2501) | W^T [2501,3077) | scatter [3077,3273) ----------
__global__ __launch_bounds__(256) void k_stage1(const float* __restrict__ feat,
                                                const float* __restrict__ wa_s,
                                                const float* __restrict__ wa_d,
                                                const float* __restrict__ W,
                                                const int* __restrict__ ei,
                                                unsigned short* __restrict__ featbf,
                                                float* __restrict__ s_s,
                                                float* __restrict__ s_d,
                                                unsigned short* __restrict__ wT,
                                                int* __restrict__ count,
                                                unsigned short* __restrict__ slots) {
  int bid = blockIdx.x, tid = threadIdx.x;
  if (bid < 2501) {                      // ---- convert feat->bf16 + fused score dots ----
    int lane = tid & 63, wv = tid >> 6;
    int r = bid * 4 + wv;
    if (r >= NNODE) return;
    const float4* fr = (const float4*)(feat + (size_t)r * HDIM);
    ushort4* ob = (ushort4*)(featbf + (size_t)r * HDIM);
    float ss = 0.f, sd = 0.f;
#pragma unroll
    for (int i = 0; i < 3; ++i) {
      int c = lane + i * 64;
      float4 v = fr[c];
      float4 vs = ((const float4*)wa_s)[c];
      float4 vd = ((const float4*)wa_d)[c];
      ss += v.x * vs.x + v.y * vs.y + v.z * vs.z + v.w * vs.w;
      sd += v.x * vd.x + v.y * vd.y + v.z * vd.z + v.w * vd.w;
      ushort4 o;
      o.x = f2bf(v.x); o.y = f2bf(v.y); o.z = f2bf(v.z); o.w = f2bf(v.w);
      ob[c] = o;
    }
#pragma unroll
    for (int off = 32; off; off >>= 1) {
      ss += __shfl_down(ss, off, 64);
      sd += __shfl_down(sd, off, 64);
    }
    if (lane == 0) { s_s[r] = ss; s_d[r] = sd; }
    return;
  }
  if (bid < 3077) {                      // ---- W -> W^T bf16, 32x32 tiles ----
    __shared__ float tile[32][33];
    int b2 = bid - 2501;
    int tx0 = (b2 % 24) * 32, ty0 = (b2 / 24) * 32;
    int cx = tid & 31, cy = tid >> 5;
#pragma unroll
    for (int r = 0; r < 4; ++r)
      tile[cy + r * 8][cx] = W[(size_t)(ty0 + cy + r * 8) * HDIM + tx0 + cx];
    __syncthreads();
#pragma unroll
    for (int r = 0; r < 4; ++r)
      wT[(size_t)(tx0 + cy + r * 8) * HDIM + ty0 + cx] = f2bf(tile[cx][cy + r * 8]);
    return;
  }
  // ---- slotted edge scatter ----
  int e = (bid - 3077) * 256 + tid;
  if (e < NEDGE) {
    int src = ei[e], dst = ei[NEDGE + e];
    int pos = atomicAdd(count + dst, 1);
    if (pos < CAP) slots[dst * CAP + pos] = (unsigned short)src;
  }
}

// ---------- K2a: gatherA (non-node output rows) + node row-list ----------
__global__ __launch_bounds__(256) void k_gatherA(const int* __restrict__ x,
                                                 const float* __restrict__ orig,
                                                 const float* __restrict__ nw,
                                                 const float* __restrict__ soft,
                                                 int* __restrict__ nct,
                                                 int* __restrict__ nlist,
                                                 float* __restrict__ out) {
  int lane = threadIdx.x & 63, wv = threadIdx.x >> 6;
  int row = blockIdx.x * 4 + wv;         // 8192 blocks * 4 = 32768 rows
  int s = row & 511;
  const float* src;
  if (s < 8) {
    src = soft + (size_t)s * HDIM;
  } else {
    int idx = x[row];
    if (idx >= VOCAB && idx < VOCAB + NNODE) {   // node token -> defer to K3
      if (lane == 0) {
        int node = idx - VOCAB;
        int p = atomicAdd(nct + node, 1);
        if (p < RCAP) nlist[node * RCAP + p] = row;
      }
      return;
    }
    src = (idx < VOCAB) ? orig + (size_t)idx * HDIM
                        : nw + (size_t)(NROWS - 1) * HDIM;
  }
  const uint4* s4 = (const uint4*)src;
  uint4* d4 = (uint4*)(out + (size_t)row * HDIM);
  d4[lane]       = s4[lane];
  d4[lane + 64]  = s4[lane + 64];
  d4[lane + 128] = s4[lane + 128];
}

// ---------- K2b: GEMM h = feat @ W  (64x128 tiles, BK=64, XOR-swizzled LDS) ----------
// Swizzle (rule #21, both-sides): LDS[row][slot16] holds global k-slot (slot16 ^ (row&7)).
// Staging keeps LDS dest linear (gl2lds requirement) and pre-swizzles the SOURCE k-offset;
// ds_read applies the same XOR. Kills the 8/16-way bank conflict of 128B-stride rows.
__global__ __launch_bounds__(256) void k_gemm(const unsigned short* __restrict__ A,
                                              const unsigned short* __restrict__ BT,
                                              unsigned short* __restrict__ Hout) {
  __shared__ __align__(16) unsigned short As[64 * 64];    // 8 KB
  __shared__ __align__(16) unsigned short Bs[128 * 64];   // 16 KB
  int b = blockIdx.x;
  int tid = threadIdx.x, lane = tid & 63, wv = tid >> 6;
  int m0 = (b % 157) * 64, n0 = (b / 157) * 128;
  int q = lane >> 4, lr = lane & 15;

  f32x4 acc[4][2];
#pragma unroll
  for (int i = 0; i < 4; ++i)
#pragma unroll
    for (int j = 0; j < 2; ++j) acc[i][j] = 0.f;

  for (int kt = 0; kt < 12; ++kt) {
    int k0 = kt * 64;
    // A-tile 64x64: 512 16B chunks, 2/thread. chunk c: row=c>>3, dest slot=c&7,
    // source k-slot = (c&7)^(row&7)  [inverse swizzle on source]
#pragma unroll
    for (int t = 0; t < 2; ++t) {
      int c = wv * 128 + t * 64 + lane;
      int row = c >> 3;
      int kk = (((c & 7) ^ (row & 7)) << 3);
      int grow = m0 + row;
      grow = grow <= NNODE - 1 ? grow : NNODE - 1;
      gl2lds16(A + (size_t)grow * HDIM + k0 + kk,
               As + (size_t)(wv * 128 + t * 64) * 8);
    }
    // B-tile 128x64: 1024 16B chunks, 4/thread
#pragma unroll
    for (int t = 0; t < 4; ++t) {
      int c = wv * 256 + t * 64 + lane;
      int row = c >> 3;
      int kk = (((c & 7) ^ (row & 7)) << 3);
      gl2lds16(BT + (size_t)(n0 + row) * HDIM + k0 + kk,
               Bs + (size_t)(wv * 256 + t * 64) * 8);
    }
    __syncthreads();
#pragma unroll
    for (int ks = 0; ks < 2; ++ks) {
      bf16x8 a[4], bb[2];
      int base = ((ks << 5) | (q << 3)) ^ ((lr & 7) << 3);   // swizzled read offset
#pragma unroll
      for (int i = 0; i < 4; ++i)
        a[i] = *(const bf16x8*)(As + (i * 16 + lr) * 64 + base);
#pragma unroll
      for (int j = 0; j < 2; ++j)
        bb[j] = *(const bf16x8*)(Bs + (wv * 32 + j * 16 + lr) * 64 + base);
#pragma unroll
      for (int i = 0; i < 4; ++i)
#pragma unroll
        for (int j = 0; j < 2; ++j)
          acc[i][j] = __builtin_amdgcn_mfma_f32_16x16x32_bf16(a[i], bb[j], acc[i][j], 0, 0, 0);
    }
    __syncthreads();
  }
#pragma unroll
  for (int i = 0; i < 4; ++i) {
    int mbase = m0 + i * 16 + q * 4;
#pragma unroll
    for (int j = 0; j < 2; ++j) {
      int n = n0 + wv * 32 + j * 16 + lr;
#pragma unroll
      for (int rg = 0; rg < 4; ++rg) {
        int m = mbase + rg;
        if (m < NNODE) Hout[(size_t)m * HDIM + n] = f2bf(acc[i][j][rg]);
      }
    }
  }
}

// ---------- K3: aggregate per needed node (wave/node) -> write DIRECT to out rows ----------
__global__ __launch_bounds__(256) void k_aggregate(const int* __restrict__ count,
                                                   const unsigned short* __restrict__ slots,
                                                   const float* __restrict__ s_s,
                                                   const float* __restrict__ s_d,
                                                   const unsigned short* __restrict__ h,
                                                   const float* __restrict__ feat,
                                                   const int* __restrict__ nct,
                                                   const int* __restrict__ nlist,
                                                   float* __restrict__ out) {
  int lane = threadIdx.x & 63, wv = threadIdx.x >> 6;
  int n = blockIdx.x * 4 + wv;           // wave = one node; lane owns 12 columns
  if (n >= NNODE) return;
  int rows = nct[n];
  if (rows == 0) return;                 // node never gathered -> no output row
  rows = rows < RCAP ? rows : RCAP;
  int deg = count[n]; deg = deg < CAP ? deg : CAP;
  const unsigned short* sl = slots + n * CAP;
  float sdn = s_d[n];
  float mx = -3.4e38f;
  for (int e = 0; e < deg; ++e) {
    float v = s_s[sl[e]] + sdn;
    v = v > 0.f ? v : SLOPE * v;
    mx = fmaxf(mx, v);
  }
  float den = 0.f;
  float acc[12];
#pragma unroll
  for (int j = 0; j < 12; ++j) acc[j] = 0.f;
  int e = 0;
  for (; e + 1 < deg; e += 2) {          // 2 independent h-row gathers in flight
    int s0 = sl[e], s1 = sl[e + 1];
    float v0 = s_s[s0] + sdn; v0 = v0 > 0.f ? v0 : SLOPE * v0;
    float v1 = s_s[s1] + sdn; v1 = v1 > 0.f ? v1 : SLOPE * v1;
    float ex0 = __expf(v0 - mx), ex1 = __expf(v1 - mx);
    den += ex0 + ex1;
    fma12(acc, ex0, h + (size_t)s0 * HDIM, lane);
    fma12(acc, ex1, h + (size_t)s1 * HDIM, lane);
  }
  if (e < deg) {
    int s0 = sl[e];
    float v0 = s_s[s0] + sdn; v0 = v0 > 0.f ? v0 : SLOPE * v0;
    float ex0 = __expf(v0 - mx);
    den += ex0;
    fma12(acc, ex0, h + (size_t)s0 * HDIM, lane);
  }
  float inv = 1.f / (den + 1e-16f);      // deg==0: acc=0 -> out=feat
  const float4* fr = (const float4*)(feat + (size_t)n * HDIM + lane * 12);
  float4 f0 = fr[0], f1 = fr[1], f2 = fr[2];
  f0.x += acc[0] * inv;  f0.y += acc[1] * inv;
  f0.z += acc[2] * inv;  f0.w += acc[3] * inv;
  f1.x += acc[4] * inv;  f1.y += acc[5] * inv;
  f1.z += acc[6] * inv;  f1.w += acc[7] * inv;
  f2.x += acc[8] * inv;  f2.y += acc[9] * inv;
  f2.z += acc[10] * inv; f2.w += acc[11] * inv;
  for (int ri = 0; ri < rows; ++ri) {
    int r = nlist[n * RCAP + ri];
    float4* d = (float4*)(out + (size_t)r * HDIM + lane * 12);
    d[0] = f0; d[1] = f1; d[2] = f2;
  }
}

// ---------- launch ----------
extern "C" void kernel_launch(void* const* d_in, const int* in_sizes, int n_in,
                              void* d_out, int out_size, void* d_ws, size_t ws_size,
                              hipStream_t stream) {
  const int* x    = (const int*)d_in[0];
  const int* ei   = (const int*)d_in[1];
  const float* og = (const float*)d_in[2];
  const float* nw = (const float*)d_in[3];
  const float* sp = (const float*)d_in[4];
  const float* W  = (const float*)d_in[5];
  const float* as = (const float*)d_in[6];
  const float* ad = (const float*)d_in[7];
  const float* feat = nw + HDIM;                  // new_weight rows 1..10002

  char* ws = (char*)d_ws;
  unsigned short* hbuf   = (unsigned short*)(ws + OFF_H);
  unsigned short* featbf = (unsigned short*)(ws + OFF_FB);
  unsigned short* wT     = (unsigned short*)(ws + OFF_WT);
  float* wa_s            = (float*)(ws + OFF_WAS);
  float* wa_d            = (float*)(ws + OFF_WAD);
  float* s_s             = (float*)(ws + OFF_SS);
  float* s_d             = (float*)(ws + OFF_SD);
  int* count             = (int*)(ws + OFF_CNT);
  int* nct               = (int*)(ws + OFF_NCT);
  unsigned short* slots  = (unsigned short*)(ws + OFF_SLOT);
  int* nlist             = (int*)(ws + OFF_NL);
  float* out             = (float*)d_out;

  // K0: wa vectors + zero counters
  k_pre<<<272, 256, 0, stream>>>(W, as, ad, wa_s, wa_d, count);
  // K1: convert+scores | W^T | slotted scatter
  k_stage1<<<3273, 256, 0, stream>>>(feat, wa_s, wa_d, W, ei,
                                     featbf, s_s, s_d, wT, count, slots);
  // K2a: gatherA (non-node rows) + node row-list
  k_gatherA<<<8192, 256, 0, stream>>>(x, og, nw, sp, nct, nlist, out);
  // K2b: GEMM h = feat @ W  (BK=64, swizzled LDS)
  k_gemm<<<942, 256, 0, stream>>>(featbf, wT, hbuf);
  // K3: aggregate -> direct output-row writes
  k_aggregate<<<(NNODE + 3) / 4, 256, 0, stream>>>(count, slots, s_s, s_d,
                                                   hbuf, feat, nct, nlist, out);
}